// Round 13
// baseline (5763.889 us; speedup 1.0000x reference)
//
#include <hip/hip_runtime.h>
#include <hip/hip_bf16.h>

// ---------------------------------------------------------------------------
// 2-layer LSTM, B=64 T=256 N=512 H=1024.
// R13: wave-specialized agents, ZERO barriers in the persistent kernel.
// Per WG (8 units/gate): wave0/1 = layer0 rowgroups 0/1 (16 rows), wave2/3 =
// layer1 rowgroups 0/1. Each wave: full K=1024 for its 32 cols (col=u*4+g ->
// cell update is wave-local), per-wave private LDS transpose (lgkmcnt only),
// 1 uncached publish store/lane + own flag word. L0 and L1 hops overlap
// fully. Write-once rings (cached loads), per-(layer,pod,rowgroup) flags.
// ---------------------------------------------------------------------------

#define T_ 256
#define B_ 64
#define N_ 512
#define H_ 1024
#define FH_ 4096
#define NWG_SEQ 256
#define BH_ (B_ * H_)

typedef _Float16 f16;
typedef _Float16 f16x4 __attribute__((ext_vector_type(4)));
typedef _Float16 f16x8 __attribute__((ext_vector_type(8)));
typedef float f32x4 __attribute__((ext_vector_type(4)));
typedef unsigned long long ull;

__device__ __forceinline__ float sigf(float x) { return 1.f / (1.f + __expf(-x)); }
__device__ __forceinline__ float tanhf_fast(float x) { return 1.f - 2.f / (__expf(2.f * x) + 1.f); }

// uncached (bypass L1/L2, MALL-coherent) accessors
__device__ __forceinline__ void st_u64g(ull* p, ull v) {
  __hip_atomic_store(p, v, __ATOMIC_RELAXED, __HIP_MEMORY_SCOPE_AGENT);
}
__device__ __forceinline__ void st_u32g(unsigned* p, unsigned v) {
  __hip_atomic_store(p, v, __ATOMIC_RELAXED, __HIP_MEMORY_SCOPE_AGENT);
}
__device__ __forceinline__ ull ld_u64g(const ull* p) {
  return __hip_atomic_load(p, __ATOMIC_RELAXED, __HIP_MEMORY_SCOPE_AGENT);
}
__device__ __forceinline__ f16x8 ld_b128_nc(const f16* p) {
  f16x8 r;
  asm volatile("global_load_dwordx4 %0, %1, off sc0 sc1" : "=v"(r) : "v"(p));
  return r;
}

// ---------------------------------------------------------------------------
// init / convert kernel
// ---------------------------------------------------------------------------
__global__ __launch_bounds__(256) void init_all(
    const float* __restrict__ x, const float* __restrict__ h,
    const float* __restrict__ Wih0, const float* __restrict__ bih0, const float* __restrict__ bhh0,
    const float* __restrict__ Whh0, const float* __restrict__ Wih1, const float* __restrict__ Whh1,
    const float* __restrict__ bih1, const float* __restrict__ bhh1,
    f16* __restrict__ xT, f16* __restrict__ wih0, f16* __restrict__ whh0,
    f16* __restrict__ wih1, f16* __restrict__ whh1,
    float* __restrict__ bias0, float* __restrict__ bias1,
    f16* __restrict__ hinit, unsigned* __restrict__ flags)
{
  const int stride = gridDim.x * blockDim.x;
  const int t0 = blockIdx.x * blockDim.x + threadIdx.x;

  for (int i = t0; i < T_ * B_ * N_; i += stride) {
    int n = i & (N_ - 1);
    int tb = i >> 9;
    int b = tb & (B_ - 1);
    int t = tb >> 6;
    xT[i] = (f16)x[((size_t)b * T_ + t) * N_ + n];
  }
  for (int i = t0; i < FH_ * N_; i += stride) wih0[i] = (f16)Wih0[i];
  for (int i = t0; i < FH_ * H_; i += stride) {
    whh0[i] = (f16)Whh0[i];
    wih1[i] = (f16)Wih1[i];
    whh1[i] = (f16)Whh1[i];
  }
  for (int i = t0; i < FH_; i += stride) {
    bias0[i] = bih0[i] + bhh0[i];
    bias1[i] = bih1[i] + bhh1[i];
  }
  for (int i = t0; i < 2 * BH_; i += stride) hinit[i] = (f16)h[i];
  if (t0 < 1024) flags[t0] = 0u;
}

// ---------------------------------------------------------------------------
// GEMM: pre0T[t][col][b] = (xT @ wih0^T + bias0), stored f16 TRANSPOSED.
// ---------------------------------------------------------------------------
__global__ __launch_bounds__(256) void gemm_pre0(
    const f16* __restrict__ xT, const f16* __restrict__ wih0,
    const float* __restrict__ bias0, f16* __restrict__ pre0T)
{
  const int wid = threadIdx.x >> 6;
  const int lane = threadIdx.x & 63;
  const int lr = lane & 15;
  const int lkq = (lane >> 4) << 3;
  const int lrq = (lane >> 4) << 2;

  const int mt = blockIdx.x & 255;
  const int ct = (blockIdx.x >> 8) * 4 + wid;
  const int row0 = mt * 64, col0 = ct * 64;

  f32x4 acc[4][4] = {};
  const f16* Abase = xT + (size_t)row0 * N_;

  #pragma unroll 2
  for (int kk = 0; kk < N_ / 32; ++kk) {
    const int k = kk * 32 + lkq;
    f16x8 a[4], b[4];
    #pragma unroll
    for (int r = 0; r < 4; ++r)
      a[r] = *(const f16x8*)(Abase + (size_t)(r * 16 + lr) * N_ + k);
    #pragma unroll
    for (int cf = 0; cf < 4; ++cf)
      b[cf] = *(const f16x8*)(wih0 + (size_t)(col0 + cf * 16 + lr) * N_ + k);
    #pragma unroll
    for (int r = 0; r < 4; ++r)
      #pragma unroll
      for (int cf = 0; cf < 4; ++cf)
        acc[r][cf] = __builtin_amdgcn_mfma_f32_16x16x32_f16(a[r], b[cf], acc[r][cf], 0, 0, 0);
  }

  #pragma unroll
  for (int r = 0; r < 4; ++r) {
    #pragma unroll
    for (int cf = 0; cf < 4; ++cf) {
      const int col = col0 + cf * 16 + lr;
      const float bv = bias0[col];
      f16x4 pv;
      #pragma unroll
      for (int ri = 0; ri < 4; ++ri) pv[ri] = (f16)(acc[r][cf][ri] + bv);
      *(f16x4*)(pre0T + ((size_t)mt * FH_ + col) * 64 + r * 16 + lrq) = pv;
    }
  }
}

// ---------------------------------------------------------------------------
// Persistent wave-agent kernel. 256 WGs x 256 threads, NO __syncthreads.
// wg: pod = wg>>7 (rows pod*32..+31), slot = wg&127, ub = slot*8.
// wave wid: role = wid>>1 (0=L0, 1=L1), rg = wid&1 (16-row group).
// Wave owns cols c=0..31 -> gate = c&3, unit = c>>2 (cell update wave-local).
// flags[((layer*2+pod)*2+rg)*128 + slot] = completed steps.
// ---------------------------------------------------------------------------
template <bool DEEP>
__global__ __launch_bounds__(256, 1) void lstm_seq(
    const f16* __restrict__ pre0T, const f16* __restrict__ whh0,
    const f16* __restrict__ wih1, const f16* __restrict__ whh1,
    const float* __restrict__ bias1, const f16* __restrict__ hinit,
    const float* __restrict__ cin,
    f16* __restrict__ h0r, f16* __restrict__ h1r,
    float* __restrict__ out, unsigned* __restrict__ flags)
{
  __shared__ __align__(16) float gexc[4][16][33];  // per-wave private
  __shared__ __align__(16) f16 hp[4][16][8];       // per-wave private

  const int tid = threadIdx.x;
  const int wid = tid >> 6;
  const int lane = tid & 63;
  const int role = wid >> 1;       // 0 = layer0, 1 = layer1
  const int rg = wid & 1;          // row-group (16 rows)

  const int wg = blockIdx.x;
  const int pod = wg >> 7;
  const int slot = wg & 127;
  const int ub = slot << 3;        // 8 units per gate
  const int r0 = pod * 32 + rg * 16;

  unsigned* f0rg = flags + (size_t)((0 * 2 + pod) * 2 + rg) * 128;
  unsigned* f1rg = flags + (size_t)((1 * 2 + pod) * 2 + rg) * 128;

  auto rt = [&](int t) -> size_t { return DEEP ? (size_t)t : (size_t)(t & 7); };

  // wave-wide poll: lane i checks flags 2i,2i+1 (128 flags, one u64/lane)
  auto waitrg = [&](const unsigned* base, unsigned tgt) {
    const ull* fp = (const ull*)base;
    for (;;) {
      ull v = ld_u64g(&fp[lane]);
      const bool ok = ((unsigned)v >= tgt) && ((unsigned)(v >> 32) >= tgt);
      if (__ballot(ok) == ~0ull) break;
      __builtin_amdgcn_s_sleep(1);
    }
    asm volatile("" ::: "memory");
  };

  // fragment geometry
  const int ar = lane & 15;          // A row within 16-row group
  const int lkq = (lane >> 4) << 3;  // k offset within 32-chunk
  // weight row for col c = cf*16 + (lane&15): gate = lane&3, unit = cf*4+((lane&15)>>2)
  const size_t wr0 = (size_t)((lane & 3) * H_ + ub + ((lane & 15) >> 2)) * H_ + lkq;
  const size_t wr1 = wr0 + (size_t)4 * H_;   // cf=1: unit += 4

  // cells: id = lane + 64*i -> row = id>>3, unit = id&7
  const int row_i[2] = { lane >> 3, (lane + 64) >> 3 };
  const int u_i[2]   = { lane & 7, (lane + 64) & 7 };

  float cst[2];
  #pragma unroll
  for (int i = 0; i < 2; ++i)
    cst[i] = cin[(size_t)role * BH_ + (size_t)(r0 + row_i[i]) * H_ + ub + u_i[i]];

  float* outh = out + (size_t)B_ * T_ * H_;
  float* outc = outh + 2 * BH_;

  if (role == 0) {
    // =========================== LAYER 0 agent ===========================
    const f16* w0 = whh0;
    for (int e = 0; e < T_; ++e) {
      // pre0 additive (cached, before poll)
      float pf[2][4];
      #pragma unroll
      for (int i = 0; i < 2; ++i)
        #pragma unroll
        for (int g = 0; g < 4; ++g)
          pf[i][g] = (float)pre0T[((size_t)e * FH_ + g * H_ + ub + u_i[i]) * 64 + r0 + row_i[i]];

      if (e > 0) waitrg(f0rg, (unsigned)e);
      if (!DEEP && e >= 8) waitrg(f1rg, (unsigned)(e - 7));

      const f16* h0s = ((e == 0) ? hinit : h0r + rt(e - 1) * BH_) + (size_t)r0 * H_;
      f16x8 a[32];
      #pragma unroll
      for (int j = 0; j < 32; ++j) {
        const f16* ap = h0s + (size_t)ar * H_ + lkq + j * 32;
        a[j] = DEEP ? *(const f16x8*)ap : ld_b128_nc(ap);
      }
      if (!DEEP) {
        asm volatile("s_waitcnt vmcnt(0)" ::: "memory");
        __builtin_amdgcn_sched_barrier(0);
      }

      f32x4 acc[2] = {};
      #pragma unroll
      for (int j = 0; j < 32; ++j) {
        f16x8 b0 = *(const f16x8*)(w0 + wr0 + j * 32);
        f16x8 b1 = *(const f16x8*)(w0 + wr1 + j * 32);
        acc[0] = __builtin_amdgcn_mfma_f32_16x16x32_f16(a[j], b0, acc[0], 0, 0, 0);
        acc[1] = __builtin_amdgcn_mfma_f32_16x16x32_f16(a[j], b1, acc[1], 0, 0, 0);
      }

      // in-wave gate transpose via private LDS (lgkmcnt only, no barrier)
      #pragma unroll
      for (int cf = 0; cf < 2; ++cf)
        #pragma unroll
        for (int ri = 0; ri < 4; ++ri)
          gexc[wid][(lane >> 4) * 4 + ri][cf * 16 + (lane & 15)] = acc[cf][ri];

      float hn[2], cn[2];
      #pragma unroll
      for (int i = 0; i < 2; ++i) {
        float gv[4];
        #pragma unroll
        for (int g = 0; g < 4; ++g)
          gv[g] = gexc[wid][row_i[i]][u_i[i] * 4 + g] + pf[i][g];
        cn[i] = sigf(gv[1]) * cst[i] + sigf(gv[0]) * tanhf_fast(gv[2]);
        hn[i] = sigf(gv[3]) * tanhf_fast(cn[i]);
        cst[i] = cn[i];
        hp[wid][row_i[i]][u_i[i]] = (f16)hn[i];
      }

      // publish: lanes 0..31, one u64 each; drain; flag
      if (lane < 32) {
        const int row = lane >> 1, half = lane & 1;
        ull v = *(const ull*)&hp[wid][row][half * 4];
        st_u64g((ull*)(h0r + rt(e) * BH_ + (size_t)(r0 + row) * H_ + ub + half * 4), v);
      }
      asm volatile("s_waitcnt vmcnt(0)" ::: "memory");
      if (lane == 0) st_u32g(&f0rg[slot], (unsigned)(e + 1));

      if (e == T_ - 1) {
        #pragma unroll
        for (int i = 0; i < 2; ++i) {
          const size_t cell = (size_t)(r0 + row_i[i]) * H_ + ub + u_i[i];
          outh[cell] = hn[i];
          outc[cell] = cn[i];
        }
      }
    }
  } else {
    // =========================== LAYER 1 agent ===========================
    float b1v[2][4];
    #pragma unroll
    for (int i = 0; i < 2; ++i)
      #pragma unroll
      for (int g = 0; g < 4; ++g)
        b1v[i][g] = bias1[g * H_ + ub + u_i[i]];

    for (int t = 0; t < T_; ++t) {
      waitrg(f0rg, (unsigned)(t + 1));   // h0[t] ready (set ~a hop ago)

      const f16* h0s = h0r + rt(t) * BH_ + (size_t)r0 * H_;
      f16x8 a[32];
      #pragma unroll
      for (int j = 0; j < 32; ++j) {
        const f16* ap = h0s + (size_t)ar * H_ + lkq + j * 32;
        a[j] = DEEP ? *(const f16x8*)ap : ld_b128_nc(ap);
      }

      if (t > 0) waitrg(f1rg, (unsigned)t);   // h1[t-1] ready (own chain)
      const f16* h1s = ((t == 0) ? hinit + BH_ : h1r + rt(t - 1) * BH_) + (size_t)r0 * H_;

      f32x4 acc[2] = {};
      // pass 1: wih1 on h0[t]
      if (!DEEP) {
        asm volatile("s_waitcnt vmcnt(0)" ::: "memory");
        __builtin_amdgcn_sched_barrier(0);
      }
      #pragma unroll
      for (int j = 0; j < 32; ++j) {
        f16x8 b0 = *(const f16x8*)(wih1 + wr0 + j * 32);
        f16x8 b1 = *(const f16x8*)(wih1 + wr1 + j * 32);
        acc[0] = __builtin_amdgcn_mfma_f32_16x16x32_f16(a[j], b0, acc[0], 0, 0, 0);
        acc[1] = __builtin_amdgcn_mfma_f32_16x16x32_f16(a[j], b1, acc[1], 0, 0, 0);
      }
      // pass 2: whh1 on h1[t-1]
      #pragma unroll
      for (int j = 0; j < 32; ++j) {
        const f16* dp = h1s + (size_t)ar * H_ + lkq + j * 32;
        f16x8 d = DEEP ? *(const f16x8*)dp : ld_b128_nc(dp);
        f16x8 b0 = *(const f16x8*)(whh1 + wr0 + j * 32);
        f16x8 b1 = *(const f16x8*)(whh1 + wr1 + j * 32);
        acc[0] = __builtin_amdgcn_mfma_f32_16x16x32_f16(d, b0, acc[0], 0, 0, 0);
        acc[1] = __builtin_amdgcn_mfma_f32_16x16x32_f16(d, b1, acc[1], 0, 0, 0);
      }

      #pragma unroll
      for (int cf = 0; cf < 2; ++cf)
        #pragma unroll
        for (int ri = 0; ri < 4; ++ri)
          gexc[wid][(lane >> 4) * 4 + ri][cf * 16 + (lane & 15)] = acc[cf][ri];

      float hn[2], cn[2];
      #pragma unroll
      for (int i = 0; i < 2; ++i) {
        float gv[4];
        #pragma unroll
        for (int g = 0; g < 4; ++g)
          gv[g] = gexc[wid][row_i[i]][u_i[i] * 4 + g] + b1v[i][g];
        cn[i] = sigf(gv[1]) * cst[i] + sigf(gv[0]) * tanhf_fast(gv[2]);
        hn[i] = sigf(gv[3]) * tanhf_fast(cn[i]);
        cst[i] = cn[i];
        hp[wid][row_i[i]][u_i[i]] = (f16)hn[i];
      }

      if (lane < 32) {
        const int row = lane >> 1, half = lane & 1;
        ull v = *(const ull*)&hp[wid][row][half * 4];
        st_u64g((ull*)(h1r + rt(t) * BH_ + (size_t)(r0 + row) * H_ + ub + half * 4), v);
      }
      asm volatile("s_waitcnt vmcnt(0)" ::: "memory");
      if (lane == 0) st_u32g(&f1rg[slot], (unsigned)(t + 1));

      // cached out writes (fire-and-forget)
      #pragma unroll
      for (int i = 0; i < 2; ++i)
        out[(size_t)(r0 + row_i[i]) * (T_ * H_) + (size_t)t * H_ + ub + u_i[i]] = hn[i];
      if (t == T_ - 1) {
        #pragma unroll
        for (int i = 0; i < 2; ++i) {
          const size_t cell = (size_t)(r0 + row_i[i]) * H_ + ub + u_i[i];
          outh[BH_ + cell] = hn[i];
          outc[BH_ + cell] = cn[i];
        }
      }
    }
  }
}

// ---------------------------------------------------------------------------
extern "C" void kernel_launch(void* const* d_in, const int* in_sizes, int n_in,
                              void* d_out, int out_size, void* d_ws, size_t ws_size,
                              hipStream_t stream)
{
  const float* x    = (const float*)d_in[0];
  const float* h    = (const float*)d_in[1];
  const float* c    = (const float*)d_in[2];
  const float* Wih0 = (const float*)d_in[3];
  const float* Whh0 = (const float*)d_in[4];
  const float* bih0 = (const float*)d_in[5];
  const float* bhh0 = (const float*)d_in[6];
  const float* Wih1 = (const float*)d_in[7];
  const float* Whh1 = (const float*)d_in[8];
  const float* bih1 = (const float*)d_in[9];
  const float* bhh1 = (const float*)d_in[10];

  char* w = (char*)d_ws;
  size_t off = 0;
  auto carve = [&](size_t bytes) -> char* {
    char* ptr = w + off;
    off = (off + bytes + 255) & ~(size_t)255;
    return ptr;
  };
  f16*   pre0T = (f16*)  carve((size_t)T_ * B_ * FH_ * 2);
  f16*   xT    = (f16*)  carve((size_t)T_ * B_ * N_ * 2);
  f16*   wih0  = (f16*)  carve((size_t)FH_ * N_ * 2);
  f16*   whh0  = (f16*)  carve((size_t)FH_ * H_ * 2);
  f16*   wih1  = (f16*)  carve((size_t)FH_ * H_ * 2);
  f16*   whh1  = (f16*)  carve((size_t)FH_ * H_ * 2);
  float* bias0 = (float*)carve((size_t)FH_ * 4);
  float* bias1 = (float*)carve((size_t)FH_ * 4);
  f16*   hinit = (f16*)  carve((size_t)2 * BH_ * 2);
  f16*   h0s   = (f16*)  carve((size_t)8 * BH_ * 2);   // shallow fallback rings
  f16*   h1s   = (f16*)  carve((size_t)8 * BH_ * 2);
  unsigned* flags = (unsigned*)carve(1024 * 4);
  const size_t base_end = off;
  f16*   h0ring = (f16*) carve((size_t)T_ * BH_ * 2);  // deep write-once rings
  f16*   h1ring = (f16*) carve((size_t)T_ * BH_ * 2);
  const bool deep = (off <= ws_size);
  if (base_end > ws_size) return;

  init_all<<<2048, 256, 0, stream>>>(x, h, Wih0, bih0, bhh0, Whh0, Wih1, Whh1, bih1, bhh1,
                                     xT, wih0, whh0, wih1, whh1, bias0, bias1, hinit, flags);
  gemm_pre0<<<4096, 256, 0, stream>>>(xT, wih0, bias0, pre0T);
  if (deep)
    lstm_seq<true><<<NWG_SEQ, 256, 0, stream>>>(pre0T, whh0, wih1, whh1, bias1, hinit,
                                                (const float*)c, h0ring, h1ring,
                                                (float*)d_out, flags);
  else
    lstm_seq<false><<<NWG_SEQ, 256, 0, stream>>>(pre0T, whh0, wih1, whh1, bias1, hinit,
                                                 (const float*)c, h0s, h1s,
                                                 (float*)d_out, flags);
}

// Round 14
// 3715.860 us; speedup vs baseline: 1.5512x; 1.5512x over previous
//
#include <hip/hip_runtime.h>
#include <hip/hip_bf16.h>

// ---------------------------------------------------------------------------
// 2-layer LSTM, B=64 T=256 N=512 H=1024.
// R14: two independent 4-wave engines per 512-thread WG. Group0 = layer0
// (R6 phase-1 geometry, 64 weight-frag VGPRs pinned), group1 = layer1 (128
// weight-frag VGPRs pinned; wih1 GEMM before the f1-gated whh1 tail). Groups
// sync internally via LDS barriers (no __syncthreads coupling), poll flags
// wave-independently, publish+flag independently -> epoch = max(hop0, hop1),
// not the sum. Write-once rings, cached consumer loads, uncached publishes.
// ---------------------------------------------------------------------------

#define T_ 256
#define B_ 64
#define N_ 512
#define H_ 1024
#define FH_ 4096
#define NWG_SEQ 256
#define BH_ (B_ * H_)

typedef _Float16 f16;
typedef _Float16 f16x4 __attribute__((ext_vector_type(4)));
typedef _Float16 f16x8 __attribute__((ext_vector_type(8)));
typedef float f32x4 __attribute__((ext_vector_type(4)));
typedef unsigned long long ull;

__device__ __forceinline__ float sigf(float x) { return 1.f / (1.f + __expf(-x)); }
__device__ __forceinline__ float tanhf_fast(float x) { return 1.f - 2.f / (__expf(2.f * x) + 1.f); }

// uncached (bypass L1/L2, MALL-coherent) accessors
__device__ __forceinline__ void st_u64g(ull* p, ull v) {
  __hip_atomic_store(p, v, __ATOMIC_RELAXED, __HIP_MEMORY_SCOPE_AGENT);
}
__device__ __forceinline__ void st_u32g(unsigned* p, unsigned v) {
  __hip_atomic_store(p, v, __ATOMIC_RELAXED, __HIP_MEMORY_SCOPE_AGENT);
}
__device__ __forceinline__ ull ld_u64g(const ull* p) {
  return __hip_atomic_load(p, __ATOMIC_RELAXED, __HIP_MEMORY_SCOPE_AGENT);
}
__device__ __forceinline__ f16x8 ld_b128_nc(const f16* p) {
  f16x8 r;
  asm volatile("global_load_dwordx4 %0, %1, off sc0 sc1" : "=v"(r) : "v"(p));
  return r;
}

// ---------------------------------------------------------------------------
// init / convert kernel
// ---------------------------------------------------------------------------
__global__ __launch_bounds__(256) void init_all(
    const float* __restrict__ x, const float* __restrict__ h,
    const float* __restrict__ Wih0, const float* __restrict__ bih0, const float* __restrict__ bhh0,
    const float* __restrict__ Whh0, const float* __restrict__ Wih1, const float* __restrict__ Whh1,
    const float* __restrict__ bih1, const float* __restrict__ bhh1,
    f16* __restrict__ xT, f16* __restrict__ wih0, f16* __restrict__ whh0,
    f16* __restrict__ wih1, f16* __restrict__ whh1,
    float* __restrict__ bias0, float* __restrict__ bias1,
    f16* __restrict__ hinit, unsigned* __restrict__ flags)
{
  const int stride = gridDim.x * blockDim.x;
  const int t0 = blockIdx.x * blockDim.x + threadIdx.x;

  for (int i = t0; i < T_ * B_ * N_; i += stride) {
    int n = i & (N_ - 1);
    int tb = i >> 9;
    int b = tb & (B_ - 1);
    int t = tb >> 6;
    xT[i] = (f16)x[((size_t)b * T_ + t) * N_ + n];
  }
  for (int i = t0; i < FH_ * N_; i += stride) wih0[i] = (f16)Wih0[i];
  for (int i = t0; i < FH_ * H_; i += stride) {
    whh0[i] = (f16)Whh0[i];
    wih1[i] = (f16)Wih1[i];
    whh1[i] = (f16)Whh1[i];
  }
  for (int i = t0; i < FH_; i += stride) {
    bias0[i] = bih0[i] + bhh0[i];
    bias1[i] = bih1[i] + bhh1[i];
  }
  for (int i = t0; i < 2 * BH_; i += stride) hinit[i] = (f16)h[i];
  if (t0 < 1024) flags[t0] = 0u;
}

// ---------------------------------------------------------------------------
// GEMM: pre0T[t][col][b] = (xT @ wih0^T + bias0), stored f16 TRANSPOSED.
// ---------------------------------------------------------------------------
__global__ __launch_bounds__(256) void gemm_pre0(
    const f16* __restrict__ xT, const f16* __restrict__ wih0,
    const float* __restrict__ bias0, f16* __restrict__ pre0T)
{
  const int wid = threadIdx.x >> 6;
  const int lane = threadIdx.x & 63;
  const int lr = lane & 15;
  const int lkq = (lane >> 4) << 3;
  const int lrq = (lane >> 4) << 2;

  const int mt = blockIdx.x & 255;
  const int ct = (blockIdx.x >> 8) * 4 + wid;
  const int row0 = mt * 64, col0 = ct * 64;

  f32x4 acc[4][4] = {};
  const f16* Abase = xT + (size_t)row0 * N_;

  #pragma unroll 2
  for (int kk = 0; kk < N_ / 32; ++kk) {
    const int k = kk * 32 + lkq;
    f16x8 a[4], b[4];
    #pragma unroll
    for (int r = 0; r < 4; ++r)
      a[r] = *(const f16x8*)(Abase + (size_t)(r * 16 + lr) * N_ + k);
    #pragma unroll
    for (int cf = 0; cf < 4; ++cf)
      b[cf] = *(const f16x8*)(wih0 + (size_t)(col0 + cf * 16 + lr) * N_ + k);
    #pragma unroll
    for (int r = 0; r < 4; ++r)
      #pragma unroll
      for (int cf = 0; cf < 4; ++cf)
        acc[r][cf] = __builtin_amdgcn_mfma_f32_16x16x32_f16(a[r], b[cf], acc[r][cf], 0, 0, 0);
  }

  #pragma unroll
  for (int r = 0; r < 4; ++r) {
    #pragma unroll
    for (int cf = 0; cf < 4; ++cf) {
      const int col = col0 + cf * 16 + lr;
      const float bv = bias0[col];
      f16x4 pv;
      #pragma unroll
      for (int ri = 0; ri < 4; ++ri) pv[ri] = (f16)(acc[r][cf][ri] + bv);
      *(f16x4*)(pre0T + ((size_t)mt * FH_ + col) * 64 + r * 16 + lrq) = pv;
    }
  }
}

// ---------------------------------------------------------------------------
// Persistent dual-engine kernel. 256 WGs x 512 threads (8 waves/CU).
// pod = wg>>7 (rows pod*32..+31), slot = wg&127, ub = slot*8.
// group g = tid>>8: 0 = layer0 engine, 1 = layer1 engine (4 waves each).
// f0 = flags + pod*128, f1 = flags + 256 + pod*128; value = steps done.
// ---------------------------------------------------------------------------
template <bool DEEP>
__global__ __launch_bounds__(512, 1) void lstm_seq(
    const f16* __restrict__ pre0T, const f16* __restrict__ whh0,
    const f16* __restrict__ wih1, const f16* __restrict__ whh1,
    const float* __restrict__ bias1, const f16* __restrict__ hinit,
    const float* __restrict__ cin,
    f16* __restrict__ h0r, f16* __restrict__ h1r,
    float* __restrict__ out, unsigned* __restrict__ flags)
{
  __shared__ __align__(16) float exc[2][4][32][33];   // [group][wave][row][col]
  __shared__ __align__(16) f16 smH[2][32][8];
  __shared__ unsigned gbar[2];

  const int tid = threadIdx.x;
  const int g = tid >> 8;          // engine: 0 = L0, 1 = L1
  const int gtid = tid & 255;
  const int p = gtid >> 6;         // wave within engine (K-quarter)
  const int lane = tid & 63;
  const int lr = lane & 15;
  const int lq = lane >> 4;
  const int lkq = lq << 3;
  const int lrq = lq << 2;

  const int wg = blockIdx.x;
  const int pod = wg >> 7;
  const int slot = wg & 127;
  const int rs = pod << 5;
  const int ub = slot << 3;        // 8 units per gate
  unsigned* f0p = flags + (pod << 7);
  unsigned* f1p = flags + 256 + (pod << 7);

  if (tid < 2) gbar[tid] = 0u;
  __syncthreads();                 // only WG-wide barrier (init)

  auto rt = [&](int t) -> size_t { return DEEP ? (size_t)t : (size_t)(t & 7); };

  unsigned bt = 0;                 // group-barrier generation (per wave)
  auto groupbar = [&]() {
    asm volatile("s_waitcnt lgkmcnt(0)" ::: "memory");
    bt += 4;
    if (lane == 0)
      __hip_atomic_fetch_add(&gbar[g], 1u, __ATOMIC_RELAXED, __HIP_MEMORY_SCOPE_WORKGROUP);
    while (__hip_atomic_load(&gbar[g], __ATOMIC_RELAXED, __HIP_MEMORY_SCOPE_WORKGROUP) < bt)
      __builtin_amdgcn_s_sleep(1);
    asm volatile("" ::: "memory");
  };

  // wave-wide poll over 128 flags (one u64 per lane); called by ALL waves
  auto waitwide = [&](const unsigned* base, unsigned tgt) {
    const ull* fp = (const ull*)base;
    for (;;) {
      ull v = ld_u64g(&fp[lane]);
      const bool ok = ((unsigned)v >= tgt) && ((unsigned)(v >> 32) >= tgt);
      if (__ballot(ok) == ~0ull) break;
      __builtin_amdgcn_s_sleep(1);
    }
    asm volatile("" ::: "memory");
  };

  // per-thread cell (within engine): crow = gtid&31, cu = gtid>>5
  const int crow = gtid & 31;
  const int cu = gtid >> 5;
  const size_t cell = (size_t)(rs + crow) * H_ + ub + cu;
  float cst = cin[(size_t)g * BH_ + cell];

  float* outh = out + (size_t)B_ * T_ * H_;
  float* outc = outh + 2 * BH_;

  if (g == 0) {
    // ======================= LAYER-0 ENGINE ==============================
    f16x8 l0w[2][8];
    #pragma unroll
    for (int cf = 0; cf < 2; ++cf) {
      const size_t wr = (size_t)((2 * cf + (lr >> 3)) * H_ + ub + (lr & 7)) * H_;
      #pragma unroll
      for (int j = 0; j < 8; ++j)
        l0w[cf][j] = *(const f16x8*)(whh0 + wr + (p * 8 + j) * 32 + lkq);
    }

    for (int e = 0; e < T_; ++e) {
      float pf[4];
      #pragma unroll
      for (int gg = 0; gg < 4; ++gg)
        pf[gg] = (float)pre0T[((size_t)e * FH_ + gg * H_ + ub + cu) * 64 + rs + crow];

      if (e > 0) waitwide(f0p, (unsigned)e);
      if (!DEEP && e >= 8) waitwide(f1p, (unsigned)(e - 7));

      const f16* h0s = ((e == 0) ? hinit : h0r + rt(e - 1) * BH_) + (size_t)rs * H_;
      f16x8 a0v[8], a1v[8];
      #pragma unroll
      for (int j = 0; j < 8; ++j) {
        const int k = (p * 8 + j) * 32 + lkq;
        if constexpr (DEEP) {
          a0v[j] = *(const f16x8*)(h0s + (size_t)lr * H_ + k);
          a1v[j] = *(const f16x8*)(h0s + (size_t)(16 + lr) * H_ + k);
        } else {
          a0v[j] = ld_b128_nc(h0s + (size_t)lr * H_ + k);
          a1v[j] = ld_b128_nc(h0s + (size_t)(16 + lr) * H_ + k);
        }
      }
      if (!DEEP) {
        asm volatile("s_waitcnt vmcnt(0)" ::: "memory");
        __builtin_amdgcn_sched_barrier(0);
      }

      f32x4 acc[2][2] = {};
      #pragma unroll
      for (int j = 0; j < 8; ++j)
        #pragma unroll
        for (int cf = 0; cf < 2; ++cf) {
          acc[cf][0] = __builtin_amdgcn_mfma_f32_16x16x32_f16(a0v[j], l0w[cf][j], acc[cf][0], 0, 0, 0);
          acc[cf][1] = __builtin_amdgcn_mfma_f32_16x16x32_f16(a1v[j], l0w[cf][j], acc[cf][1], 0, 0, 0);
        }
      #pragma unroll
      for (int cf = 0; cf < 2; ++cf)
        #pragma unroll
        for (int rf = 0; rf < 2; ++rf)
          #pragma unroll
          for (int ri = 0; ri < 4; ++ri)
            exc[0][p][rf * 16 + lrq + ri][cf * 16 + lr] = acc[cf][rf][ri];
      groupbar();   // exc complete

      float gv[4];
      #pragma unroll
      for (int gg = 0; gg < 4; ++gg)
        gv[gg] = exc[0][0][crow][gg * 8 + cu] + exc[0][1][crow][gg * 8 + cu]
               + exc[0][2][crow][gg * 8 + cu] + exc[0][3][crow][gg * 8 + cu] + pf[gg];
      const float cn = sigf(gv[1]) * cst + sigf(gv[0]) * tanhf_fast(gv[2]);
      const float hn = sigf(gv[3]) * tanhf_fast(cn);
      cst = cn;
      smH[0][crow][cu] = (f16)hn;
      groupbar();   // smH complete

      if (p == 0) {
        const int row = lane >> 1, half = lane & 1;
        ull v = *(const ull*)&smH[0][row][half * 4];
        st_u64g((ull*)(h0r + rt(e) * BH_ + (size_t)(rs + row) * H_ + ub + half * 4), v);
        asm volatile("s_waitcnt vmcnt(0)" ::: "memory");
        if (lane == 0) st_u32g(&f0p[slot], (unsigned)(e + 1));
      }

      if (e == T_ - 1) { outh[cell] = hn; outc[cell] = cn; }
    }
  } else {
    // ======================= LAYER-1 ENGINE ==============================
    f16x8 l1aw[2][8], l1bw[2][8];
    #pragma unroll
    for (int cf = 0; cf < 2; ++cf) {
      const size_t wr = (size_t)((2 * cf + (lr >> 3)) * H_ + ub + (lr & 7)) * H_;
      #pragma unroll
      for (int j = 0; j < 8; ++j) {
        const int k = (p * 8 + j) * 32 + lkq;
        l1aw[cf][j] = *(const f16x8*)(wih1 + wr + k);
        l1bw[cf][j] = *(const f16x8*)(whh1 + wr + k);
      }
    }
    float b1v[4];
    #pragma unroll
    for (int gg = 0; gg < 4; ++gg) b1v[gg] = bias1[gg * H_ + ub + cu];

    for (int t = 0; t < T_; ++t) {
      waitwide(f0p, (unsigned)(t + 1));   // h0[t] ready (L0 runs ahead)
      const f16* h0s = h0r + rt(t) * BH_ + (size_t)rs * H_;
      f16x8 a0v[8], a1v[8];
      #pragma unroll
      for (int j = 0; j < 8; ++j) {
        const int k = (p * 8 + j) * 32 + lkq;
        if constexpr (DEEP) {
          a0v[j] = *(const f16x8*)(h0s + (size_t)lr * H_ + k);
          a1v[j] = *(const f16x8*)(h0s + (size_t)(16 + lr) * H_ + k);
        } else {
          a0v[j] = ld_b128_nc(h0s + (size_t)lr * H_ + k);
          a1v[j] = ld_b128_nc(h0s + (size_t)(16 + lr) * H_ + k);
        }
      }
      if (!DEEP) {
        asm volatile("s_waitcnt vmcnt(0)" ::: "memory");
        __builtin_amdgcn_sched_barrier(0);
      }

      // wih1 GEMM first (independent of h1 hop)
      f32x4 acc[2][2] = {};
      #pragma unroll
      for (int j = 0; j < 8; ++j)
        #pragma unroll
        for (int cf = 0; cf < 2; ++cf) {
          acc[cf][0] = __builtin_amdgcn_mfma_f32_16x16x32_f16(a0v[j], l1aw[cf][j], acc[cf][0], 0, 0, 0);
          acc[cf][1] = __builtin_amdgcn_mfma_f32_16x16x32_f16(a1v[j], l1aw[cf][j], acc[cf][1], 0, 0, 0);
        }

      // f1-gated whh1 tail (the only serial part of L1's recurrence)
      if (t > 0) waitwide(f1p, (unsigned)t);
      const f16* h1s = ((t == 0) ? hinit + BH_ : h1r + rt(t - 1) * BH_) + (size_t)rs * H_;
      f16x8 d0v[8], d1v[8];
      #pragma unroll
      for (int j = 0; j < 8; ++j) {
        const int k = (p * 8 + j) * 32 + lkq;
        if constexpr (DEEP) {
          d0v[j] = *(const f16x8*)(h1s + (size_t)lr * H_ + k);
          d1v[j] = *(const f16x8*)(h1s + (size_t)(16 + lr) * H_ + k);
        } else {
          d0v[j] = ld_b128_nc(h1s + (size_t)lr * H_ + k);
          d1v[j] = ld_b128_nc(h1s + (size_t)(16 + lr) * H_ + k);
        }
      }
      if (!DEEP) {
        asm volatile("s_waitcnt vmcnt(0)" ::: "memory");
        __builtin_amdgcn_sched_barrier(0);
      }
      #pragma unroll
      for (int j = 0; j < 8; ++j)
        #pragma unroll
        for (int cf = 0; cf < 2; ++cf) {
          acc[cf][0] = __builtin_amdgcn_mfma_f32_16x16x32_f16(d0v[j], l1bw[cf][j], acc[cf][0], 0, 0, 0);
          acc[cf][1] = __builtin_amdgcn_mfma_f32_16x16x32_f16(d1v[j], l1bw[cf][j], acc[cf][1], 0, 0, 0);
        }

      #pragma unroll
      for (int cf = 0; cf < 2; ++cf)
        #pragma unroll
        for (int rf = 0; rf < 2; ++rf)
          #pragma unroll
          for (int ri = 0; ri < 4; ++ri)
            exc[1][p][rf * 16 + lrq + ri][cf * 16 + lr] = acc[cf][rf][ri];
      groupbar();   // exc complete

      float gv[4];
      #pragma unroll
      for (int gg = 0; gg < 4; ++gg)
        gv[gg] = exc[1][0][crow][gg * 8 + cu] + exc[1][1][crow][gg * 8 + cu]
               + exc[1][2][crow][gg * 8 + cu] + exc[1][3][crow][gg * 8 + cu] + b1v[gg];
      const float cn = sigf(gv[1]) * cst + sigf(gv[0]) * tanhf_fast(gv[2]);
      const float hn = sigf(gv[3]) * tanhf_fast(cn);
      cst = cn;
      smH[1][crow][cu] = (f16)hn;
      groupbar();   // smH complete

      if (p == 0) {
        const int row = lane >> 1, half = lane & 1;
        ull v = *(const ull*)&smH[1][row][half * 4];
        st_u64g((ull*)(h1r + rt(t) * BH_ + (size_t)(rs + row) * H_ + ub + half * 4), v);
        asm volatile("s_waitcnt vmcnt(0)" ::: "memory");
        if (lane == 0) st_u32g(&f1p[slot], (unsigned)(t + 1));
      }

      out[(size_t)(rs + crow) * (T_ * H_) + (size_t)t * H_ + ub + cu] = hn;
      if (t == T_ - 1) { outh[BH_ + cell] = hn; outc[BH_ + cell] = cn; }
    }
  }
}

// ---------------------------------------------------------------------------
extern "C" void kernel_launch(void* const* d_in, const int* in_sizes, int n_in,
                              void* d_out, int out_size, void* d_ws, size_t ws_size,
                              hipStream_t stream)
{
  const float* x    = (const float*)d_in[0];
  const float* h    = (const float*)d_in[1];
  const float* c    = (const float*)d_in[2];
  const float* Wih0 = (const float*)d_in[3];
  const float* Whh0 = (const float*)d_in[4];
  const float* bih0 = (const float*)d_in[5];
  const float* bhh0 = (const float*)d_in[6];
  const float* Wih1 = (const float*)d_in[7];
  const float* Whh1 = (const float*)d_in[8];
  const float* bih1 = (const float*)d_in[9];
  const float* bhh1 = (const float*)d_in[10];

  char* w = (char*)d_ws;
  size_t off = 0;
  auto carve = [&](size_t bytes) -> char* {
    char* ptr = w + off;
    off = (off + bytes + 255) & ~(size_t)255;
    return ptr;
  };
  f16*   pre0T = (f16*)  carve((size_t)T_ * B_ * FH_ * 2);
  f16*   xT    = (f16*)  carve((size_t)T_ * B_ * N_ * 2);
  f16*   wih0  = (f16*)  carve((size_t)FH_ * N_ * 2);
  f16*   whh0  = (f16*)  carve((size_t)FH_ * H_ * 2);
  f16*   wih1  = (f16*)  carve((size_t)FH_ * H_ * 2);
  f16*   whh1  = (f16*)  carve((size_t)FH_ * H_ * 2);
  float* bias0 = (float*)carve((size_t)FH_ * 4);
  float* bias1 = (float*)carve((size_t)FH_ * 4);
  f16*   hinit = (f16*)  carve((size_t)2 * BH_ * 2);
  f16*   h0s   = (f16*)  carve((size_t)8 * BH_ * 2);   // shallow fallback rings
  f16*   h1s   = (f16*)  carve((size_t)8 * BH_ * 2);
  unsigned* flags = (unsigned*)carve(1024 * 4);
  const size_t base_end = off;
  f16*   h0ring = (f16*) carve((size_t)T_ * BH_ * 2);  // deep write-once rings
  f16*   h1ring = (f16*) carve((size_t)T_ * BH_ * 2);
  const bool deep = (off <= ws_size);
  if (base_end > ws_size) return;

  init_all<<<2048, 256, 0, stream>>>(x, h, Wih0, bih0, bhh0, Whh0, Wih1, Whh1, bih1, bhh1,
                                     xT, wih0, whh0, wih1, whh1, bias0, bias1, hinit, flags);
  gemm_pre0<<<4096, 256, 0, stream>>>(xT, wih0, bias0, pre0T);
  if (deep)
    lstm_seq<true><<<NWG_SEQ, 512, 0, stream>>>(pre0T, whh0, wih1, whh1, bias1, hinit,
                                                (const float*)c, h0ring, h1ring,
                                                (float*)d_out, flags);
  else
    lstm_seq<false><<<NWG_SEQ, 512, 0, stream>>>(pre0T, whh0, wih1, whh1, bias1, hinit,
                                                 (const float*)c, h0s, h1s,
                                                 (float*)d_out, flags);
}